// Round 10
// baseline (212.711 us; speedup 1.0000x reference)
//
#include <hip/hip_runtime.h>
#include <math.h>

#define BATCH 4
#define SEQ   1024
#define DIM_C 1024
#define HEADS 16
#define HDIM  64
#define F3    3072

typedef short bf8 __attribute__((ext_vector_type(8)));
typedef float f32x4 __attribute__((ext_vector_type(4)));

__device__ __forceinline__ ushort f2bf(float f) {
    union { float f; unsigned u; } c; c.f = f;
    unsigned u = c.u + 0x7fffu + ((c.u >> 16) & 1u);
    return (ushort)(u >> 16);
}
__device__ __forceinline__ float bf2f(ushort s) {
    union { unsigned u; float f; } c; c.u = ((unsigned)s) << 16;
    return c.f;
}

// async 16B global -> LDS (wave-uniform LDS base; lane*16 is implicit)
__device__ __forceinline__ void stage16(const ushort* g, ushort* l) {
    __builtin_amdgcn_global_load_lds(
        (const __attribute__((address_space(1))) unsigned int*)g,
        (__attribute__((address_space(3))) unsigned int*)l, 16, 0, 0);
}

// ---------------------------------------------------------------------------
// fp32 -> bf16 bulk convert: x (2048 blks) | Wqkv (1536) | Wproj (512)
// ---------------------------------------------------------------------------
__global__ __launch_bounds__(256) void cvt_all_kernel(
    const float* __restrict__ x, const float* __restrict__ wqkv,
    const float* __restrict__ wproj,
    ushort* __restrict__ xb, ushort* __restrict__ wqkvb,
    ushort* __restrict__ wprojb)
{
    const int blk = blockIdx.x;
    const float* src; ushort* dst; size_t off;
    if (blk < 2048)      { src = x;     dst = xb;     off = (size_t)blk * 2048; }
    else if (blk < 3584) { src = wqkv;  dst = wqkvb;  off = (size_t)(blk - 2048) * 2048; }
    else                 { src = wproj; dst = wprojb; off = (size_t)(blk - 3584) * 2048; }
    size_t i = off + (size_t)threadIdx.x * 8;
    float4 v0 = *(const float4*)&src[i];
    float4 v1 = *(const float4*)&src[i + 4];
    ushort o[8];
    o[0] = f2bf(v0.x); o[1] = f2bf(v0.y); o[2] = f2bf(v0.z); o[3] = f2bf(v0.w);
    o[4] = f2bf(v1.x); o[5] = f2bf(v1.y); o[6] = f2bf(v1.z); o[7] = f2bf(v1.w);
    *(uint4*)&dst[i] = *(uint4*)o;
}

// ---------------------------------------------------------------------------
// Er fp32 -> fragment-packed bf16: erp[rt][c][lane][8] = Er[rt*16+lc][c*32+g4*8+j]
// (lane = g4*16+lc). rt 0..67; rows >=1024 zero-padded (feed masked entries).
// Grid 17 x 256.
// ---------------------------------------------------------------------------
__global__ __launch_bounds__(256) void er_pack_kernel(
    const float* __restrict__ er, ushort* __restrict__ erp)
{
    const int tid = blockIdx.x * 256 + threadIdx.x;   // 0..4351
    const int rt = tid >> 6, lane = tid & 63;
    const int lc = lane & 15, g4 = lane >> 4;
    const int row = rt * 16 + lc;
    #pragma unroll
    for (int c = 0; c < 2; ++c) {
        ushort o[8] = {0, 0, 0, 0, 0, 0, 0, 0};
        if (row < 1024) {
            float4 a = *(const float4*)&er[(size_t)row * 64 + c * 32 + g4 * 8];
            float4 q = *(const float4*)&er[(size_t)row * 64 + c * 32 + g4 * 8 + 4];
            o[0] = f2bf(a.x); o[1] = f2bf(a.y); o[2] = f2bf(a.z); o[3] = f2bf(a.w);
            o[4] = f2bf(q.x); o[5] = f2bf(q.y); o[6] = f2bf(q.z); o[7] = f2bf(q.w);
        }
        *(uint4*)&erp[(size_t)rt * 1024 + c * 512 + lane * 8] = *(uint4*)o;
    }
}

// ---------------------------------------------------------------------------
// m97-style MFMA GEMM core (unchanged)
// ---------------------------------------------------------------------------
__device__ __forceinline__ void gemm_core(
    const ushort* __restrict__ a, const ushort* __restrict__ b,
    ushort* As, ushort* Bs, int m0, int f0, int t, f32x4 (&acc)[4][4])
{
    const int lane = t & 63, w = t >> 6;
    const int lc = lane & 15, g4 = lane >> 4;
    const int wm = (w >> 1) * 64, wn = (w & 1) * 64;
    const int rowS = w * 32 + (lane >> 2);
    const int kkS  = (lane & 3) * 8;

    for (int kt = 0; kt < 32; ++kt) {
        const int k0 = kt * 32;
        __syncthreads();
        #pragma unroll
        for (int ii = 0; ii < 2; ++ii) {
            stage16(&a[(size_t)(m0 + rowS + ii * 16) * 1024 + k0 + kkS],
                    &As[(w * 2 + ii) * 512]);
            stage16(&b[(size_t)(f0 + rowS + ii * 16) * 1024 + k0 + kkS],
                    &Bs[(w * 2 + ii) * 512]);
        }
        __syncthreads();
        bf8 af[4], bfr[4];
        #pragma unroll
        for (int mb = 0; mb < 4; ++mb)
            af[mb] = *(const bf8*)&As[(wm + mb * 16 + lc) * 32 + g4 * 8];
        #pragma unroll
        for (int nb = 0; nb < 4; ++nb)
            bfr[nb] = *(const bf8*)&Bs[(wn + nb * 16 + lc) * 32 + g4 * 8];
        #pragma unroll
        for (int mb = 0; mb < 4; ++mb)
            #pragma unroll
            for (int nb = 0; nb < 4; ++nb)
                acc[mb][nb] = __builtin_amdgcn_mfma_f32_16x16x32_bf16(
                    af[mb], bfr[nb], acc[mb][nb], 0, 0, 0);
    }
}

// qkv GEMM: writes q/k/v in DENSE fragment-packed layouts:
//   q,k: off = (n>>4)*1024 + (d>>5)*512 + ((d>>3)&3)*128 + (n&15)*8 + (d&7)
//   v:   off = (n>>6)*4096 + (d>>4)*1024 + ((n>>5)&1)*512 + ((n>>3)&3)*128
//             + (d&15)*8 + (n&7)        [16 kt * 4096 = 65536 per (b,h)]
__global__ __launch_bounds__(256) void gemm_qkv_mfma(
    const ushort* __restrict__ xb, const ushort* __restrict__ wb,
    ushort* __restrict__ qp, ushort* __restrict__ kp, ushort* __restrict__ vp)
{
    __shared__ __align__(16) ushort As[128 * 32];
    __shared__ __align__(16) ushort Bs[128 * 32];
    const int t = threadIdx.x;
    const int m0 = blockIdx.y * 128, f0 = blockIdx.x * 128;
    f32x4 acc[4][4];
    #pragma unroll
    for (int mb = 0; mb < 4; ++mb)
        #pragma unroll
        for (int nb = 0; nb < 4; ++nb) acc[mb][nb] = (f32x4){0.f, 0.f, 0.f, 0.f};

    gemm_core(xb, wb, As, Bs, m0, f0, t, acc);

    const int lane = t & 63, w = t >> 6;
    const int lc = lane & 15, g4 = lane >> 4;
    const int wm = (w >> 1) * 64, wn = (w & 1) * 64;
    const int s = f0 >> 10;                      // uniform: 0=q 1=k 2=v
    #pragma unroll
    for (int mb = 0; mb < 4; ++mb)
        #pragma unroll
        for (int nb = 0; nb < 4; ++nb) {
            const int f = f0 + wn + nb * 16 + lc;
            const int h = (f >> 6) & 15, d = f & 63;
            #pragma unroll
            for (int i = 0; i < 4; ++i) {
                const int m = m0 + wm + mb * 16 + g4 * 4 + i;
                const int b = m >> 10, n = m & 1023;
                const size_t bho = (size_t)(b * 16 + h) * 65536;
                const ushort val = f2bf(acc[mb][nb][i]);
                if (s == 0)
                    qp[bho + (n >> 4) * 1024 + (d >> 5) * 512 + ((d >> 3) & 3) * 128
                           + (n & 15) * 8 + (d & 7)] = val;
                else if (s == 1)
                    kp[bho + (n >> 4) * 1024 + (d >> 5) * 512 + ((d >> 3) & 3) * 128
                           + (n & 15) * 8 + (d & 7)] = val;
                else
                    vp[bho + (n >> 6) * 4096 + (d >> 4) * 1024 + ((n >> 5) & 1) * 512
                           + ((n >> 3) & 3) * 128 + (d & 15) * 8 + (n & 7)] = val;
            }
        }
}

// proj: +bias, fp32 out (unchanged)
__global__ __launch_bounds__(256) void gemm_proj_mfma(
    const ushort* __restrict__ ab, const ushort* __restrict__ wb,
    const float* __restrict__ bias, float* __restrict__ y)
{
    __shared__ __align__(16) ushort As[128 * 32];
    __shared__ __align__(16) ushort Bs[128 * 32];
    const int t = threadIdx.x;
    const int m0 = blockIdx.y * 128, f0 = blockIdx.x * 128;
    f32x4 acc[4][4];
    #pragma unroll
    for (int mb = 0; mb < 4; ++mb)
        #pragma unroll
        for (int nb = 0; nb < 4; ++nb) acc[mb][nb] = (f32x4){0.f, 0.f, 0.f, 0.f};

    gemm_core(ab, wb, As, Bs, m0, f0, t, acc);

    const int lane = t & 63, w = t >> 6;
    const int lc = lane & 15, g4 = lane >> 4;
    const int wm = (w >> 1) * 64, wn = (w & 1) * 64;
    #pragma unroll
    for (int mb = 0; mb < 4; ++mb)
        #pragma unroll
        for (int nb = 0; nb < 4; ++nb) {
            const int f = f0 + wn + nb * 16 + lc;
            const float bv = bias[f];
            #pragma unroll
            for (int i = 0; i < 4; ++i) {
                const int m = m0 + wm + mb * 16 + g4 * 4 + i;
                y[(size_t)m * 1024 + f] = acc[mb][nb][i] + bv;
            }
        }
}

// ---------------------------------------------------------------------------
// Split-K MFMA flash attention, BARRIER-FREE. All MFMA fragments (Q, K, Er,
// V^T) are coalesced 16B/lane loads from fragment-packed global buffers
// (L1/L2-resident). Only the per-wave R-gather and P C->A transpose use LDS.
// Fixed-max softmax; partials combine by summation (attn_combine_kernel).
// ---------------------------------------------------------------------------
__global__ __launch_bounds__(256, 3) void attn_mfma_kernel(
    const ushort* __restrict__ qp, const ushort* __restrict__ kp,
    const ushort* __restrict__ vp, const ushort* __restrict__ erp,
    ushort* __restrict__ pOd, float* __restrict__ pL)
{
    __shared__ float r_s[4][16][84];
    __shared__ __align__(16) ushort p_s[4][16][72];

    const int t = threadIdx.x;
    const int w = t >> 6, lane = t & 63;
    const int lc = lane & 15, g4 = lane >> 4;
    const int b = blockIdx.z, h = blockIdx.y;
    const int u = blockIdx.x;                     // 0..39
    const int cum[17] = {0,1,2,3,4,6,8,10,12,15,18,21,24,28,32,36,40};
    int bx = 0;
    #pragma unroll
    for (int j = 1; j < 16; ++j) if (u >= cum[j]) bx = j;
    const int part = u - cum[bx];
    const int t0 = part * 4;
    const int t1 = min(t0 + 4, bx + 1);

    const int n0w = bx * 64 + w * 16;
    const size_t bho = (size_t)(b * 16 + h) * 65536;
    const ushort* qb = qp + bho;
    const ushort* kb = kp + bho;
    const ushort* vb = vp + bho;

    // Q A-fragments (coalesced packed load)
    bf8 qf[2];
    #pragma unroll
    for (int c = 0; c < 2; ++c)
        qf[c] = *(const bf8*)&qb[(size_t)(bx * 4 + w) * 1024 + c * 512 + lane * 8];

    const f32x4 z4 = {0.f, 0.f, 0.f, 0.f};
    f32x4 od[4] = {z4, z4, z4, z4};
    float lrow[4] = {0.f, 0.f, 0.f, 0.f};

    for (int tt = t0; tt < t1; ++tt) {
        const int m0 = tt * 64;
        const int rte = (15 - bx + tt) * 4 + (3 - w);   // Er rt base for this wave

        // K B-fragments (coalesced)
        bf8 kf[4][2];
        #pragma unroll
        for (int jt = 0; jt < 4; ++jt)
            #pragma unroll
            for (int c = 0; c < 2; ++c)
                kf[jt][c] = *(const bf8*)&kb[(size_t)(tt * 4 + jt) * 1024 + c * 512 + lane * 8];
        // Er B-fragments (coalesced; rt >= 64 reads zero-pad -> masked entries)
        bf8 ef[5][2];
        #pragma unroll
        for (int jr = 0; jr < 5; ++jr)
            #pragma unroll
            for (int c = 0; c < 2; ++c)
                ef[jr][c] = *(const bf8*)&erp[(size_t)(rte + jr) * 1024 + c * 512 + lane * 8];

        // content scores S[16][64]
        f32x4 sc[4] = {z4, z4, z4, z4};
        #pragma unroll
        for (int jt = 0; jt < 4; ++jt)
            #pragma unroll
            for (int c = 0; c < 2; ++c)
                sc[jt] = __builtin_amdgcn_mfma_f32_16x16x32_bf16(qf[c], kf[jt][c], sc[jt], 0, 0, 0);

        // rel tile R[16][80]
        f32x4 rc[5] = {z4, z4, z4, z4, z4};
        #pragma unroll
        for (int jr = 0; jr < 5; ++jr)
            #pragma unroll
            for (int c = 0; c < 2; ++c)
                rc[jr] = __builtin_amdgcn_mfma_f32_16x16x32_bf16(qf[c], ef[jr][c], rc[jr], 0, 0, 0);

        // V^T B-fragments (dense packed: tt*4096 + dt*1024 + c*512 + lane*8)
        bf8 vf[4][2];
        #pragma unroll
        for (int dt = 0; dt < 4; ++dt)
            #pragma unroll
            for (int c = 0; c < 2; ++c)
                vf[dt][c] = *(const bf8*)&vb[(size_t)(tt * 4096 + dt * 1024 + c * 512) + lane * 8];

        // R -> LDS (f32, C-layout) for the diagonal gather (per-wave slice)
        #pragma unroll
        for (int jr = 0; jr < 5; ++jr)
            #pragma unroll
            for (int i = 0; i < 4; ++i)
                r_s[w][g4 * 4 + i][jr * 16 + lc] = rc[jr][i];
        asm volatile("s_waitcnt lgkmcnt(0)" ::: "memory");

        // p = exp((sc+rel)/8), masked; accumulate l per-lane
        #pragma unroll
        for (int i = 0; i < 4; ++i) {
            const int row = g4 * 4 + i;
            const int n = n0w + row;
            #pragma unroll
            for (int jt = 0; jt < 4; ++jt) {
                const int colR = jt * 16 + lc + 15 - row;   // in [0,78]
                const float rel = r_s[w][row][colR];
                const float s = (sc[jt][i] + rel) * 0.125f;
                const int m = m0 + jt * 16 + lc;
                const float p = (m <= n) ? __expf(s) : 0.f;
                p_s[w][row][jt * 16 + lc] = f2bf(p);
                lrow[i] += p;
            }
        }
        asm volatile("s_waitcnt lgkmcnt(0)" ::: "memory");

        // PV: A = P (A-layout from per-wave LDS), B = V^T fragments
        bf8 pf[2];
        #pragma unroll
        for (int c = 0; c < 2; ++c)
            pf[c] = *(const bf8*)&p_s[w][lc][c * 32 + g4 * 8];
        #pragma unroll
        for (int dt = 0; dt < 4; ++dt)
            #pragma unroll
            for (int c = 0; c < 2; ++c)
                od[dt] = __builtin_amdgcn_mfma_f32_16x16x32_bf16(pf[c], vf[dt][c], od[dt], 0, 0, 0);
    }

    // epilogue: reduce l over the 16 lc lanes; write unnormalized partials
    #pragma unroll
    for (int off = 1; off < 16; off <<= 1)
        #pragma unroll
        for (int i = 0; i < 4; ++i)
            lrow[i] += __shfl_xor(lrow[i], off, 16);

    const size_t pbase = (size_t)((b * 16 + h) * 40 + u);
    #pragma unroll
    for (int i = 0; i < 4; ++i) {
        const int nl = w * 16 + g4 * 4 + i;
        #pragma unroll
        for (int dt = 0; dt < 4; ++dt)
            pOd[pbase * 4096 + nl * 64 + dt * 16 + lc] = f2bf(od[dt][i]);
        if (lc == 0) pL[pbase * 64 + nl] = lrow[i];
    }
}

// ---------------------------------------------------------------------------
// Combine: sum <=4 partials per (bh, n-chunk), normalize, write bf16 attnb.
// ---------------------------------------------------------------------------
__global__ __launch_bounds__(256) void attn_combine_kernel(
    const ushort* __restrict__ pOd, const float* __restrict__ pL,
    ushort* __restrict__ attnb)
{
    const int tid = blockIdx.x * 256 + threadIdx.x;
    const int d8 = tid & 7;
    const int n  = (tid >> 3) & 1023;
    const int bh = tid >> 13;
    const int bx = n >> 6, nl = n & 63;
    const int cum[17] = {0,1,2,3,4,6,8,10,12,15,18,21,24,28,32,36,40};
    const int u0 = cum[bx], pc = cum[bx + 1] - cum[bx];

    float acc[8] = {0.f, 0.f, 0.f, 0.f, 0.f, 0.f, 0.f, 0.f};
    float lsum = 0.f;
    for (int j = 0; j < pc; ++j) {
        const size_t base = (size_t)(bh * 40 + u0 + j);
        uint4 pv = *(const uint4*)&pOd[base * 4096 + nl * 64 + d8 * 8];
        const ushort* pp = (const ushort*)&pv;
        #pragma unroll
        for (int e = 0; e < 8; ++e) acc[e] += bf2f(pp[e]);
        lsum += pL[base * 64 + nl];
    }
    const float inv = 1.f / lsum;
    ushort o[8];
    #pragma unroll
    for (int e = 0; e < 8; ++e) o[e] = f2bf(acc[e] * inv);
    const int b = bh >> 4, h = bh & 15;
    *(uint4*)&attnb[((size_t)(b * 1024) + n) * 1024 + h * 64 + d8 * 8] = *(uint4*)o;
}

// ---------------------------------------------------------------------------
extern "C" void kernel_launch(void* const* d_in, const int* in_sizes, int n_in,
                              void* d_out, int out_size, void* d_ws, size_t ws_size,
                              hipStream_t stream)
{
    const float* x     = (const float*)d_in[0];
    const float* Wqkv  = (const float*)d_in[1];
    const float* Wproj = (const float*)d_in[2];
    const float* bproj = (const float*)d_in[3];
    const float* Er    = (const float*)d_in[4];
    float* out = (float*)d_out;

    const size_t per = (size_t)BATCH * HEADS * SEQ * HDIM;   // 4,194,304
    ushort* xb     = (ushort*)d_ws;
    ushort* wqkvb  = xb + (size_t)4194304;
    ushort* wprojb = wqkvb + (size_t)3145728;
    ushort* erp    = wprojb + (size_t)1048576;    // 68*1024 = 69,632 (slot 131072)
    ushort* qw     = erp + (size_t)131072;
    ushort* kw     = qw + per;
    ushort* vw     = kw + per;
    ushort* attnb  = vw + per;
    ushort* pOd    = attnb + per;                 // 64*40*4096 bf16 = 21 MB
    float*  pL     = (float*)(pOd + (size_t)64 * 40 * 4096);  // 64*40*64 f32

    cvt_all_kernel<<<dim3(4096), 256, 0, stream>>>(
        x, Wqkv, Wproj, xb, wqkvb, wprojb);

    er_pack_kernel<<<dim3(17), 256, 0, stream>>>(Er, erp);

    gemm_qkv_mfma<<<dim3(F3 / 128, (BATCH * SEQ) / 128), 256, 0, stream>>>(
        xb, wqkvb, qw, kw, vw);

    attn_mfma_kernel<<<dim3(40, HEADS, BATCH), 256, 0, stream>>>(
        qw, kw, vw, erp, pOd, pL);

    attn_combine_kernel<<<dim3(2048), 256, 0, stream>>>(pOd, pL, attnb);

    gemm_proj_mfma<<<dim3(DIM_C / 128, (BATCH * SEQ) / 128), 256, 0, stream>>>(
        attnb, wprojb, bproj, out);
}